// Round 6
// baseline (330.606 us; speedup 1.0000x reference)
//
// LinOSS layer (B=16, N=4096, q=256) on MI355X gfx950.
// Round 6: I/O contract resolved — inputs fp32 AND outputs fp32 (reference
// returns fp32; the "(bf16)" in the assert label is literal template text).
// R1/R4 NaN = fp32 inputs misread as bf16; R2/R3/R5 identical 9.22 = bf16
// written into an fp32-read d_out. Pipeline (zero-risk aliasing, ws optional):
//   gemm1: u @ W_B^T + b_B -> fx = dt*s*Bu (fp32) into y-region of d_out
//   scan:  3-phase chunked linear recurrence (16 chunks x 256), fp32, fx -> y
//          IN PLACE (falls back to monolithic scan if ws_size < 1 MiB)
//   gemm2: y @ W_C^T + u @ W_D^T + biases -> erf-GELU -> g*sigmoid(g) + u
//          -> out0 (first half of d_out, overwritten last).
// GEMM: 128x128 tile, BK=32, 4 waves 2x2, mfma_f32_16x16x32_bf16, fp32
// operands converted to bf16 during LDS staging (fp32 accumulate), LDS rows
// padded to 40 bf16 (16B-aligned rows, <=2-way bank aliasing = free).

#include <hip/hip_runtime.h>
#include <hip/hip_bf16.h>
#include <cstdint>

typedef __bf16 bf16_t;
typedef __bf16 bf16x8 __attribute__((ext_vector_type(8)));
typedef float f32x4 __attribute__((ext_vector_type(4)));

#define B_SZ 16
#define N_SZ 4096
#define Q_SZ 256
#define M_TOT (B_SZ * N_SZ) /* 65536 */
#define DT (1.0f / 4096.0f)
#define LDST 40 /* LDS row stride in bf16 elems */
#define CHUNKS 16
#define CLEN (N_SZ / CHUNKS) /* 256 */

// load 8 contiguous fp32, convert to bf16x8
__device__ __forceinline__ bf16x8 load8f(const float* p) {
  const float4 v0 = *(const float4*)p;
  const float4 v1 = *(const float4*)(p + 4);
  bf16x8 v;
  v[0] = (bf16_t)v0.x; v[1] = (bf16_t)v0.y; v[2] = (bf16_t)v0.z; v[3] = (bf16_t)v0.w;
  v[4] = (bf16_t)v1.x; v[5] = (bf16_t)v1.y; v[6] = (bf16_t)v1.z; v[7] = (bf16_t)v1.w;
  return v;
}

// One K=256 pass of a 128x128 tile. A: [M,256] fp32 rows from m0,
// Bm: [256,256] fp32 rows from n0; contraction over the fast (K) dim of both.
__device__ __forceinline__ void kloop(const float* __restrict__ Ap,
                                      const float* __restrict__ Bp,
                                      int m0, int n0, int t,
                                      bf16_t* As, bf16_t* Bs, f32x4 acc[4][4]) {
  const int r = t >> 2, cc = t & 3;
  const int lane = t & 63, ln = lane & 15, quad = lane >> 4;
  const int wave = t >> 6;
  const int wm = (wave & 1) * 64, wn = (wave >> 1) * 64;

  for (int k0 = 0; k0 < Q_SZ; k0 += 32) {
#pragma unroll
    for (int i = 0; i < 2; ++i) {
      const int row = r + i * 64;
      const int col = k0 + cc * 8;
      *(bf16x8*)(As + row * LDST + cc * 8) =
          load8f(Ap + (size_t)(m0 + row) * Q_SZ + col);
      *(bf16x8*)(Bs + row * LDST + cc * 8) =
          load8f(Bp + (size_t)(n0 + row) * Q_SZ + col);
    }
    __syncthreads();
    bf16x8 af[4], bv[4];
#pragma unroll
    for (int mi = 0; mi < 4; ++mi) {
      af[mi] = *(const bf16x8*)(As + (wm + mi * 16 + ln) * LDST + quad * 8);
      bv[mi] = *(const bf16x8*)(Bs + (wn + mi * 16 + ln) * LDST + quad * 8);
    }
#pragma unroll
    for (int mi = 0; mi < 4; ++mi)
#pragma unroll
      for (int ni = 0; ni < 4; ++ni)
        acc[mi][ni] = __builtin_amdgcn_mfma_f32_16x16x32_bf16(af[mi], bv[ni],
                                                              acc[mi][ni], 0, 0, 0);
    __syncthreads();
  }
}

// GEMM1: fx[m,p] = dt*s_p*(sum_q u[m,q] WB[p,q] + bB[p]) -> fp32 (y region)
__global__ __launch_bounds__(256) void gemm1_kernel(
    const float* __restrict__ u, const float* __restrict__ WB,
    const float* __restrict__ a, const float* __restrict__ bB,
    float* __restrict__ fx) {
  __shared__ __align__(16) bf16_t As[128 * LDST];
  __shared__ __align__(16) bf16_t Bs[128 * LDST];
  const int t = threadIdx.x;
  const int m0 = blockIdx.x * 128, n0 = blockIdx.y * 128;
  f32x4 acc[4][4] = {};
  kloop(u, WB, m0, n0, t, As, Bs, acc);

  const int lane = t & 63, ln = lane & 15, quad = lane >> 4;
  const int wave = t >> 6;
  const int wm = (wave & 1) * 64, wn = (wave >> 1) * 64;
#pragma unroll
  for (int ni = 0; ni < 4; ++ni) {
    const int gp = n0 + wn + ni * 16 + ln; // D: col = lane&15
    const float av = a[gp];
    const float s = 1.0f / (1.0f + DT * DT * av);
    const float sc = DT * s;
    const float bb = bB[gp];
#pragma unroll
    for (int mi = 0; mi < 4; ++mi) {
      const int gm = m0 + wm + mi * 16 + quad * 4; // D: row = quad*4+reg
#pragma unroll
      for (int r2 = 0; r2 < 4; ++r2)
        fx[(size_t)(gm + r2) * Q_SZ + gp] = sc * (acc[mi][ni][r2] + bb);
    }
  }
}

// ---- scan (3-phase chunked) ----
#define PF 8

// phase 1: per (b,chunk,p), scan CLEN steps from zero init -> end state
__global__ __launch_bounds__(256) void scan1_kernel(
    const float* __restrict__ fx, const float* __restrict__ a,
    float* __restrict__ ex, float* __restrict__ ez) {
  const int g = blockIdx.x * 256 + threadIdx.x; // 0..65535
  const int p = g & 255, c = (g >> 8) & (CHUNKS - 1), b = g >> 12;
  const float av = a[p];
  const float s = 1.0f / (1.0f + DT * DT * av);
  const float dsa = DT * s * av, dss = DT * s;
  float x = 0.f, z = 0.f;
  const float* fp = fx + ((size_t)b * N_SZ + c * CLEN) * Q_SZ + p;
  float buf[PF], nbuf[PF];
#pragma unroll
  for (int j = 0; j < PF; ++j) buf[j] = fp[(size_t)j * Q_SZ];
  for (int n = 0; n < CLEN; n += PF) {
    if (n + PF < CLEN) {
#pragma unroll
      for (int j = 0; j < PF; ++j) nbuf[j] = fp[(size_t)(n + PF + j) * Q_SZ];
    }
#pragma unroll
    for (int j = 0; j < PF; ++j) {
      const float f = buf[j];
      const float xn = fmaf(s, x, fmaf(-dsa, z, f));
      const float zn = fmaf(dss, x, fmaf(s, z, DT * f));
      x = xn; z = zn;
    }
#pragma unroll
    for (int j = 0; j < PF; ++j) buf[j] = nbuf[j];
  }
  ex[g] = x; ez[g] = z;
}

// phase 2: compose chunk initial states: S_{c+1} = M^CLEN * S_c + E_c
__global__ __launch_bounds__(256) void scan2_kernel(
    const float* __restrict__ a, const float* __restrict__ ex,
    const float* __restrict__ ez, float* __restrict__ ix, float* __restrict__ iz) {
  const int g = blockIdx.x * 256 + threadIdx.x; // 0..4095
  const int p = g & 255, b = g >> 8;
  const float av = a[p];
  const float s = 1.0f / (1.0f + DT * DT * av);
  float m00 = s, m01 = -DT * s * av, m10 = DT * s, m11 = s;
#pragma unroll
  for (int i = 0; i < 8; ++i) { // M^(2^8) = M^CLEN
    const float a00 = fmaf(m00, m00, m01 * m10);
    const float a01 = m01 * (m00 + m11);
    const float a10 = m10 * (m00 + m11);
    const float a11 = fmaf(m11, m11, m01 * m10);
    m00 = a00; m01 = a01; m10 = a10; m11 = a11;
  }
  float x = 0.f, z = 0.f;
  for (int c = 0; c < CHUNKS; ++c) {
    const size_t idx = ((size_t)b * CHUNKS + c) * Q_SZ + p;
    ix[idx] = x; iz[idx] = z;
    const float xn = fmaf(m00, x, fmaf(m01, z, ex[idx]));
    const float zn = fmaf(m10, x, fmaf(m11, z, ez[idx]));
    x = xn; z = zn;
  }
}

// phase 3: rescan each chunk from its true initial state; y overwrites fx
__global__ __launch_bounds__(256) void scan3_kernel(
    const float* __restrict__ a, const float* __restrict__ ix,
    const float* __restrict__ iz, float* __restrict__ yf) {
  const int g = blockIdx.x * 256 + threadIdx.x;
  const int p = g & 255, c = (g >> 8) & (CHUNKS - 1), b = g >> 12;
  const float av = a[p];
  const float s = 1.0f / (1.0f + DT * DT * av);
  const float dsa = DT * s * av, dss = DT * s;
  float x = ix[g], z = iz[g];
  float* yp = yf + ((size_t)b * N_SZ + c * CLEN) * Q_SZ + p;
  float buf[PF], nbuf[PF];
#pragma unroll
  for (int j = 0; j < PF; ++j) buf[j] = yp[(size_t)j * Q_SZ];
  for (int n = 0; n < CLEN; n += PF) {
    if (n + PF < CLEN) {
#pragma unroll
      for (int j = 0; j < PF; ++j) nbuf[j] = yp[(size_t)(n + PF + j) * Q_SZ];
    }
#pragma unroll
    for (int j = 0; j < PF; ++j) {
      const float f = buf[j];
      const float xn = fmaf(s, x, fmaf(-dsa, z, f));
      const float zn = fmaf(dss, x, fmaf(s, z, DT * f));
      x = xn; z = zn;
      yp[(size_t)(n + j) * Q_SZ] = zn;
    }
#pragma unroll
    for (int j = 0; j < PF; ++j) buf[j] = nbuf[j];
  }
}

// monolithic fallback scan (used only if ws_size is too small)
__global__ __launch_bounds__(256) void scan_mono_kernel(
    const float* __restrict__ a, float* __restrict__ yf) {
  const int g = blockIdx.x * 256 + threadIdx.x; // 0..4095
  const int p = g & 255, b = g >> 8;
  const float av = a[p];
  const float s = 1.0f / (1.0f + DT * DT * av);
  const float dsa = DT * s * av, dss = DT * s;
  float x = 0.f, z = 0.f;
  float* yp = yf + (size_t)b * N_SZ * Q_SZ + p;
  float buf[PF], nbuf[PF];
#pragma unroll
  for (int j = 0; j < PF; ++j) buf[j] = yp[(size_t)j * Q_SZ];
  for (int n = 0; n < N_SZ; n += PF) {
    if (n + PF < N_SZ) {
#pragma unroll
      for (int j = 0; j < PF; ++j) nbuf[j] = yp[(size_t)(n + PF + j) * Q_SZ];
    }
#pragma unroll
    for (int j = 0; j < PF; ++j) {
      const float f = buf[j];
      const float xn = fmaf(s, x, fmaf(-dsa, z, f));
      const float zn = fmaf(dss, x, fmaf(s, z, DT * f));
      x = xn; z = zn;
      yp[(size_t)(n + j) * Q_SZ] = zn;
    }
#pragma unroll
    for (int j = 0; j < PF; ++j) buf[j] = nbuf[j];
  }
}

// GEMM2: x = y@WC^T + u@WD^T + bC + bD; g = gelu_erf(x); out0 = g*sigmoid(g)+u
__global__ __launch_bounds__(256) void gemm2_kernel(
    const float* __restrict__ y, const float* __restrict__ WC,
    const float* __restrict__ u, const float* __restrict__ WD,
    const float* __restrict__ bC, const float* __restrict__ bD,
    float* __restrict__ out0) {
  __shared__ __align__(16) bf16_t As[128 * LDST];
  __shared__ __align__(16) bf16_t Bs[128 * LDST];
  const int t = threadIdx.x;
  const int m0 = blockIdx.x * 128, n0 = blockIdx.y * 128;
  f32x4 acc[4][4] = {};
  kloop(y, WC, m0, n0, t, As, Bs, acc);
  kloop(u, WD, m0, n0, t, As, Bs, acc);

  const int lane = t & 63, ln = lane & 15, quad = lane >> 4;
  const int wave = t >> 6;
  const int wm = (wave & 1) * 64, wn = (wave >> 1) * 64;
#pragma unroll
  for (int ni = 0; ni < 4; ++ni) {
    const int gp = n0 + wn + ni * 16 + ln;
    const float bias = bC[gp] + bD[gp];
#pragma unroll
    for (int mi = 0; mi < 4; ++mi) {
      const int gm = m0 + wm + mi * 16 + quad * 4;
#pragma unroll
      for (int r2 = 0; r2 < 4; ++r2) {
        const float x = acc[mi][ni][r2] + bias;
        const float g = 0.5f * x * (1.0f + erff(x * 0.70710678118654752f));
        const float sg = 1.0f / (1.0f + __expf(-g));
        const float uu = u[(size_t)(gm + r2) * Q_SZ + gp];
        out0[(size_t)(gm + r2) * Q_SZ + gp] = fmaf(g, sg, uu);
      }
    }
  }
}

extern "C" void kernel_launch(void* const* d_in, const int* in_sizes, int n_in,
                              void* d_out, int out_size, void* d_ws, size_t ws_size,
                              hipStream_t stream) {
  const float* u  = (const float*)d_in[0];
  const float* a  = (const float*)d_in[1];
  const float* WB = (const float*)d_in[2];
  const float* bB = (const float*)d_in[3];
  const float* WC = (const float*)d_in[4];
  const float* bC = (const float*)d_in[5];
  const float* WD = (const float*)d_in[6];
  const float* bD = (const float*)d_in[7];

  float* out0 = (float*)d_out;                // first 16.7M fp32: out
  float* yreg = out0 + (size_t)M_TOT * Q_SZ;  // second 16.7M fp32: fx -> y

  dim3 gg(M_TOT / 128, Q_SZ / 128);
  gemm1_kernel<<<gg, 256, 0, stream>>>(u, WB, a, bB, yreg);

  const size_t state_bytes = 4 * (size_t)M_TOT * sizeof(float); // 1 MiB
  if (ws_size >= state_bytes) {
    float* ex = (float*)d_ws;
    float* ez = ex + M_TOT;
    float* ix = ez + M_TOT;
    float* iz = ix + M_TOT;
    scan1_kernel<<<256, 256, 0, stream>>>(yreg, a, ex, ez);
    scan2_kernel<<<16, 256, 0, stream>>>(a, ex, ez, ix, iz);
    scan3_kernel<<<256, 256, 0, stream>>>(a, ix, iz, yreg);
  } else {
    scan_mono_kernel<<<16, 256, 0, stream>>>(a, yreg);
  }

  gemm2_kernel<<<gg, 256, 0, stream>>>(yreg, WC, u, WD, bC, bD, out0);
}